// Round 8
// baseline (366.446 us; speedup 1.0000x reference)
//
#include <hip/hip_runtime.h>

typedef unsigned short ushort;
typedef unsigned int uint;
typedef __attribute__((ext_vector_type(8))) short short8;
typedef __attribute__((ext_vector_type(4))) float float4v;

#define D_MODEL 1024
#define NH 16
#define DH 64
#define BATCH 2
#define SEQ 1024
#define MEMLEN 1024
#define TOT 2048

__device__ __forceinline__ float b2f(ushort u) {
  return __uint_as_float(((uint)u) << 16);
}
__device__ __forceinline__ ushort f2b(float f) {
  uint i = __float_as_uint(f);
  uint r = (i + 0x7fffu + ((i >> 16) & 1u)) >> 16;
  return (ushort)r;
}
__device__ __forceinline__ void gld16(const ushort* g, ushort* l) {
  __builtin_amdgcn_global_load_lds(
      (const __attribute__((address_space(1))) void*)g,
      (__attribute__((address_space(3))) void*)l, 16, 0, 0);
}

// ---------------- fused preprocessing: concat+cast, rel cast, mask cast -----
__global__ __launch_bounds__(256) void preproc_kernel(
    const float* __restrict__ x, const float* __restrict__ mem,
    const float* __restrict__ rel, const float* __restrict__ mask,
    ushort* __restrict__ xt, ushort* __restrict__ xb,
    ushort* __restrict__ relb, ushort* __restrict__ maskb) {
  const int bid = blockIdx.x;
  if (bid < 2048) {
    int idx = bid * 256 + threadIdx.x;
    int row = idx >> 7;
    int c8 = (idx & 127) << 3;
    int b = row >> 11;
    int i = row & 2047;
    const float* src = (i < MEMLEN) ? &mem[((b << 10) + i) * D_MODEL]
                                    : &x[((b << 10) + (i - MEMLEN)) * D_MODEL];
    float4 f0 = *(const float4*)(&src[c8]);
    float4 f1 = *(const float4*)(&src[c8 + 4]);
    ushort u[8] = {f2b(f0.x), f2b(f0.y), f2b(f0.z), f2b(f0.w),
                   f2b(f1.x), f2b(f1.y), f2b(f1.z), f2b(f1.w)};
    *(uint4*)(&xt[row * D_MODEL + c8]) = *(const uint4*)u;
    if (i >= MEMLEN)
      *(uint4*)(&xb[((b << 10) + (i - MEMLEN)) * D_MODEL + c8]) =
          *(const uint4*)u;
  } else if (bid < 3072) {
    int idx = (bid - 2048) * 256 + threadIdx.x;
    int base = idx << 3;
    float4 f0 = *(const float4*)(&rel[base]);
    float4 f1 = *(const float4*)(&rel[base + 4]);
    ushort u[8] = {f2b(f0.x), f2b(f0.y), f2b(f0.z), f2b(f0.w),
                   f2b(f1.x), f2b(f1.y), f2b(f1.z), f2b(f1.w)};
    *(uint4*)(&relb[base]) = *(const uint4*)u;
  } else {
    int idx = (bid - 3072) * 256 + threadIdx.x;
    int base = idx << 3;
    float4 f0 = *(const float4*)(&mask[base]);
    float4 f1 = *(const float4*)(&mask[base + 4]);
    ushort u[8] = {f2b(f0.x * -1e9f), f2b(f0.y * -1e9f), f2b(f0.z * -1e9f),
                   f2b(f0.w * -1e9f), f2b(f1.x * -1e9f), f2b(f1.y * -1e9f),
                   f2b(f1.z * -1e9f), f2b(f1.w * -1e9f)};
    *(uint4*)(&maskb[base]) = *(const uint4*)u;
  }
}

// --------------------------- 5x transpose + cast to bf16 (one launch) -------
__global__ __launch_bounds__(256) void transpose_cvt5_kernel(
    const float* __restrict__ W0, const float* __restrict__ W1,
    const float* __restrict__ W2, const float* __restrict__ W3,
    const float* __restrict__ W4, ushort* __restrict__ T0,
    ushort* __restrict__ T1, ushort* __restrict__ T2, ushort* __restrict__ T3,
    ushort* __restrict__ T4) {
  __shared__ ushort tle[32][33];
  const float* W;
  ushort* T;
  switch (blockIdx.z) {
    case 0: W = W0; T = T0; break;
    case 1: W = W1; T = T1; break;
    case 2: W = W2; T = T2; break;
    case 3: W = W3; T = T3; break;
    default: W = W4; T = T4; break;
  }
  const int bx = blockIdx.x * 32, by = blockIdx.y * 32;
  const int tx = threadIdx.x & 31, ty = threadIdx.x >> 5;
#pragma unroll
  for (int j = 0; j < 32; j += 8)
    tle[ty + j][tx] = f2b(W[(by + ty + j) * 1024 + bx + tx]);
  __syncthreads();
#pragma unroll
  for (int j = 0; j < 32; j += 8)
    T[(bx + ty + j) * 1024 + by + tx] = tle[tx][ty + j];
}

// --------------- fused projection GEMM: KV + q + qrel in one launch ---------
// seg0 (bid<512): K cols -> kv (scaled 0.125, bke); V cols -> written DIRECTLY
//   TRANSPOSED into kv's V-half via split-row mapping.
// seg1 (bid>=512): qr = xbrel @ (WqT | WkrT by row); qrel rows scaled 0.125.
__global__ __launch_bounds__(256) void gemm_fused_kernel(
    const ushort* __restrict__ xt, const ushort* __restrict__ xbrel,
    const ushort* __restrict__ WkeT, const ushort* __restrict__ WqT,
    const ushort* __restrict__ WkrT, const float* __restrict__ bke,
    const float* __restrict__ bv, const float* __restrict__ bq,
    const float* __restrict__ bkr, ushort* __restrict__ kv,
    ushort* __restrict__ qr) {
  __shared__ ushort As[128 * 32];
  __shared__ ushort Bs[128 * 32];
  const int bid = blockIdx.x;
  const bool seg0 = (bid < 512);
  const ushort* A;
  const ushort* BT;
  int m0, n0;
  if (seg0) {
    m0 = (bid & 31) * 128;
    n0 = (bid >> 5) * 128;
    A = xt;
    BT = WkeT;   // rows >=1024 fall through into adjacent WvT
  } else {
    int g = bid - 512;
    m0 = (g & 31) * 128;
    n0 = (g >> 5) * 128;
    A = xbrel;
    BT = (m0 < 2048) ? WqT : WkrT;
  }
  const int tid = threadIdx.x;
  const int w = tid >> 6, lane = tid & 63, m15 = lane & 15, q4 = lane >> 4;
  const int wm = w & 1, wn = w >> 1;
  float4v acc[4][4] = {};
  const int c0 = tid, c1 = tid + 256;
  const int r0 = c0 >> 2, u0 = (c0 & 3) * 8;
  const int r1 = c1 >> 2, u1 = (c1 & 3) * 8;

  for (int kk = 0; kk < 1024; kk += 32) {
    __syncthreads();
    gld16(&A[(m0 + r0) * 1024 + kk + u0], &As[c0 * 8]);
    gld16(&A[(m0 + r1) * 1024 + kk + u1], &As[c1 * 8]);
    gld16(&BT[(n0 + r0) * 1024 + kk + u0], &Bs[c0 * 8]);
    gld16(&BT[(n0 + r1) * 1024 + kk + u1], &Bs[c1 * 8]);
    __syncthreads();
    short8 af[4], bf[4];
#pragma unroll
    for (int i = 0; i < 4; ++i)
      af[i] = *(const short8*)(&As[(wm * 64 + i * 16 + m15) * 32 + q4 * 8]);
#pragma unroll
    for (int j = 0; j < 4; ++j)
      bf[j] = *(const short8*)(&Bs[(wn * 64 + j * 16 + m15) * 32 + q4 * 8]);
#pragma unroll
    for (int i = 0; i < 4; ++i)
#pragma unroll
      for (int j = 0; j < 4; ++j)
        acc[i][j] =
            __builtin_amdgcn_mfma_f32_16x16x32_bf16(af[i], bf[j], acc[i][j], 0, 0, 0);
  }
#pragma unroll
  for (int j = 0; j < 4; ++j) {
    int col = n0 + wn * 64 + j * 16 + m15;
    if (seg0) {
      if (col < 1024) {
        float bb = bke[col];
#pragma unroll
        for (int i = 0; i < 4; ++i) {
          int rowb = m0 + wm * 64 + i * 16 + q4 * 4;
#pragma unroll
          for (int r = 0; r < 4; ++r)
            kv[(rowb + r) * 2048 + col] = f2b((acc[i][j][r] + bb) * 0.125f);
        }
      } else {
        float bb = bv[col - 1024];
#pragma unroll
        for (int i = 0; i < 4; ++i) {
          int rowb = m0 + wm * 64 + i * 16 + q4 * 4;
          int dg = ((rowb >> 11) << 10) + (col - 1024);
          size_t prow = (size_t)(dg * 2 + ((rowb >> 10) & 1)) * 2048 + 1024 +
                        (rowb & 1023);
          uint lo = (uint)f2b(acc[i][j][0] + bb) |
                    ((uint)f2b(acc[i][j][1] + bb) << 16);
          uint hi = (uint)f2b(acc[i][j][2] + bb) |
                    ((uint)f2b(acc[i][j][3] + bb) << 16);
          *(uint2*)(&kv[prow]) = make_uint2(lo, hi);
        }
      }
    } else {
      float bb = (m0 < 2048) ? bq[col] : bkr[col];
      float sc = (m0 < 2048) ? 1.0f : 0.125f;
#pragma unroll
      for (int i = 0; i < 4; ++i) {
        int rowb = m0 + wm * 64 + i * 16 + q4 * 4;
#pragma unroll
        for (int r = 0; r < 4; ++r)
          qr[(rowb + r) * 1024 + col] = f2b((acc[i][j][r] + bb) * sc);
      }
    }
  }
}

// -------------------------------------- 64x128-tile GEMM (output proj) ------
template <int EPI>
__global__ __launch_bounds__(256) void gemm64_kernel(
    const ushort* __restrict__ A, const ushort* __restrict__ BT,
    const float* __restrict__ bias, void* __restrict__ Cout, int M, int N,
    int K) {
  __shared__ ushort As[64 * 32];
  __shared__ ushort Bs[128 * 32];
  const int m0 = blockIdx.x * 64, n0 = blockIdx.y * 128;
  const int tid = threadIdx.x;
  const int w = tid >> 6, lane = tid & 63, m15 = lane & 15, q4 = lane >> 4;
  float4v acc[4][2] = {};
  const int ra = tid >> 2, ua = (tid & 3) * 8;
  const int c0 = tid, c1 = tid + 256;
  const int rb0 = c0 >> 2, ub0 = (c0 & 3) * 8;
  const int rb1 = c1 >> 2, ub1 = (c1 & 3) * 8;

  for (int kk = 0; kk < K; kk += 32) {
    __syncthreads();
    gld16(&A[(m0 + ra) * K + kk + ua], &As[tid * 8]);
    gld16(&BT[(n0 + rb0) * K + kk + ub0], &Bs[c0 * 8]);
    gld16(&BT[(n0 + rb1) * K + kk + ub1], &Bs[c1 * 8]);
    __syncthreads();
    short8 bf[2];
#pragma unroll
    for (int j = 0; j < 2; ++j)
      bf[j] = *(const short8*)(&Bs[(w * 32 + j * 16 + m15) * 32 + q4 * 8]);
#pragma unroll
    for (int i = 0; i < 4; ++i) {
      short8 af = *(const short8*)(&As[(i * 16 + m15) * 32 + q4 * 8]);
#pragma unroll
      for (int j = 0; j < 2; ++j)
        acc[i][j] =
            __builtin_amdgcn_mfma_f32_16x16x32_bf16(af, bf[j], acc[i][j], 0, 0, 0);
    }
  }
#pragma unroll
  for (int j = 0; j < 2; ++j) {
    int col = n0 + w * 32 + j * 16 + m15;
    float bv = bias[col];
#pragma unroll
    for (int i = 0; i < 4; ++i) {
      int rowb = m0 + i * 16 + q4 * 4;
#pragma unroll
      for (int r = 0; r < 4; ++r) {
        float v = acc[i][j][r] + bv;
        if (EPI == 1)
          ((float*)Cout)[(rowb + r) * N + col] = v;
        else
          ((ushort*)Cout)[(rowb + r) * N + col] = f2b(v);
      }
    }
  }
}

// ----------------------- Bhat batched GEMM + mask fold ----------------------
// Bh[b,h,sp,u] = q[sp].Qrel[u] (Qrel pre-scaled 1/8) + mask for the (s,t)
// cell that will READ this element in attn. Band-A reads (u >= 1023-sp,
// consumer (sp, t=u+sp-1023)) and wrap reads (u < 1023-sp, consumer
// (sp-1, t=u+sp+1025)) are provably disjoint, so exactly one mask value is
// correct per cell. Mask reads are row-contiguous (L2-hot, 4 MB).
__global__ __launch_bounds__(256) void bhat_kernel(
    const ushort* __restrict__ q, const ushort* __restrict__ Qrb,
    const ushort* __restrict__ maskb, ushort* __restrict__ Bh) {
  __shared__ ushort As[2 * 128 * 32];
  __shared__ ushort Bs[2 * 128 * 32];
  const int bs0 = blockIdx.x * 128, u0 = blockIdx.y * 128, h = blockIdx.z;
  const int tid = threadIdx.x;
  const int w = tid >> 6, lane = tid & 63, m15 = lane & 15, q4 = lane >> 4;
  const int wm = w & 1, wn = w >> 1;

#pragma unroll
  for (int c = 0; c < 4; ++c) {
    int unit = c * 256 + tid;               // flat LDS ushort = unit*8
    int row = (unit >> 2) & 127, kh = unit >> 9, cu = unit & 3;
    gld16(&q[(bs0 + row) * 1024 + (h << 6) + kh * 32 + cu * 8], &As[unit * 8]);
    gld16(&Qrb[(u0 + row) * 1024 + (h << 6) + kh * 32 + cu * 8], &Bs[unit * 8]);
  }
  __syncthreads();

  float4v acc[4][4] = {};
#pragma unroll
  for (int kh = 0; kh < 2; ++kh) {
    short8 af[4], bf[4];
#pragma unroll
    for (int i = 0; i < 4; ++i)
      af[i] = *(const short8*)(&As[kh * 4096 + (wm * 64 + i * 16 + m15) * 32 + q4 * 8]);
#pragma unroll
    for (int j = 0; j < 4; ++j)
      bf[j] = *(const short8*)(&Bs[kh * 4096 + (wn * 64 + j * 16 + m15) * 32 + q4 * 8]);
#pragma unroll
    for (int i = 0; i < 4; ++i)
#pragma unroll
      for (int j = 0; j < 4; ++j)
        acc[i][j] =
            __builtin_amdgcn_mfma_f32_16x16x32_bf16(af[i], bf[j], acc[i][j], 0, 0, 0);
  }
  const int b = bs0 >> 10;
  const int s0loc = bs0 & 1023;
  const int outrow0 = ((b << 4) + h) * 1024 + s0loc;
#pragma unroll
  for (int j = 0; j < 4; ++j) {
    int u = u0 + wn * 64 + j * 16 + m15;
#pragma unroll
    for (int i = 0; i < 4; ++i) {
      int rowb = outrow0 + wm * 64 + i * 16 + q4 * 4;
      int spb = s0loc + wm * 64 + i * 16 + q4 * 4;
#pragma unroll
      for (int r = 0; r < 4; ++r) {
        int sp = spb + r;
        bool selA = (u >= 1023 - sp);
        int mrow = selA ? sp : (sp > 0 ? sp - 1 : 0);
        int mcol = selA ? (u + sp - 1023) : (u + sp + 1025);
        float mval = b2f(maskb[mrow * 2048 + mcol]);
        Bh[(rowb + r) * 2048 + u] = f2b(acc[i][j][r] + mval);
      }
    }
  }
}

// ---- fused attention: age-ordered uniform software pipeline (in-order VM) --
// wave = (st s-tile 16 rows, th T-half). Chunk = 32 t, 32 chunks/wave.
// IN-ORDER VMEM RULE: a wait on load X forces completion of all loads issued
// before X. Therefore ALL streams are prefetched at non-decreasing distances:
//   K/V at distance 2 (ring of 4 static slots), Bh at distance 4 (ring of 4),
//   per-chunk issue order [KV(c+2)] -> [Bh(c+4)] -> compute(c).
// The KV(c) wait (issued 2 chunks ago) only drains Bh(<=c+2); Bh(c+4) stays
// in flight ~3 chunks (~1200cy > 900cy HBM). sched_barrier(0x38F) pins VMEM
// issue order (ALU/MFMA/DS may cross). ILP replaces TLP: ~2 waves/SIMD.
__global__ __launch_bounds__(256, 2) void attn_kernel(
    const ushort* __restrict__ qb, const ushort* __restrict__ kv,
    const ushort* __restrict__ Bh, const ushort* __restrict__ maskb,
    ushort* __restrict__ attn) {
  __shared__ ushort Pp[4][16 * 36];
  __shared__ float comb[2][16][68];
  __shared__ float csum[32];

  const int tid = threadIdx.x;
  const int w = tid >> 6, lane = tid & 63, m15 = lane & 15, q4 = lane >> 4;
  const int st = w & 1, th = w >> 1;
  const int s0w = blockIdx.x * 32 + st * 16;
  const int h = blockIdx.y, b = blockIdx.z;
  const int s_l = q4 * 4;

  const ushort* qp = &qb[((b << 10) + s0w + m15) * 1024 + (h << 6) + q4 * 8];
  const short8 af0 = *(const short8*)qp;
  const short8 af1 = *(const short8*)(qp + 32);

  const ushort* kvb = &kv[((size_t)(b << 11) * 2048) + (h << 6)];
  const ushort* vrowb =
      &kv[((size_t)(((b << 10) + (h << 6)) << 1) + th) * 2048 + 1024];
  const int bhbase = ((b << 4) + h) << 21;   // *(1024*2048)
  ushort* pw = &Pp[w][0];

  int offA[4], offB[4], diagT[4];
  float dm[4];
#pragma unroll
  for (int i = 0; i < 4; ++i) {
    int s = s0w + s_l + i;
    offA[i] = bhbase + (s << 11) - s + 1023;
    offB[i] = bhbase + ((s + 1) << 11) - s - 1026;
    diagT[i] = s + 1025;
    dm[i] = (diagT[i] <= 2047) ? b2f(maskb[s * 2048 + diagT[i]]) : 0.f;
  }

  float lsum4[4] = {0.f, 0.f, 0.f, 0.f};
  float4v oacc[4] = {};
  const int tb = th * 1024;

  auto ldKV = [&](int c, short8 (&K)[2][2], short8 (&V)[4]) {
    const int t0 = tb + c * 32;
#pragma unroll
    for (int nt = 0; nt < 2; ++nt) {
      const ushort* kp = &kvb[(size_t)(t0 + nt * 16 + m15) * 2048 + q4 * 8];
      K[nt][0] = *(const short8*)kp;
      K[nt][1] = *(const short8*)(kp + 32);
    }
    const int tc = c * 32 + q4 * 8;
#pragma unroll
    for (int nd = 0; nd < 4; ++nd)
      V[nd] = *(const short8*)(&vrowb[(size_t)(nd * 16 + m15) * 4096 + tc]);
  };
  auto ldB = [&](int c, ushort (&B)[8]) {
    const int t0 = tb + c * 32;
#pragma unroll
    for (int nt = 0; nt < 2; ++nt)
#pragma unroll
      for (int i = 0; i < 4; ++i) {
        int t = t0 + nt * 16 + m15;
        int off = (t < diagT[i]) ? offA[i] : offB[i];
        B[nt * 4 + i] = Bh[off + t];
      }
  };

  auto chunk = [&](int c, short8 (&K)[2][2], short8 (&V)[4],
                   short8 (&Kp)[2][2], short8 (&Vp)[4], ushort (&Bs)[8]) {
    // consume Bh(c) out of its ring slot first (slot is re-issued below)
    ushort cur[8];
#pragma unroll
    for (int j = 0; j < 8; ++j) cur[j] = Bs[j];
    // issue KV(c+2) (older than the Bh reissue below)
    if (c + 2 < 32) ldKV(c + 2, Kp, Vp);
    __builtin_amdgcn_sched_barrier(0x38F);   // pin VMEM order
    // issue Bh(c+4) — youngest; survives the next two KV waits
    if (c + 4 < 32) ldB(c + 4, Bs);
    __builtin_amdgcn_sched_barrier(0x38F);
    // compute chunk c (K/V issued 2 chunks ago; Bh 4 chunks ago)
    float4v a0 = {}, a1 = {};
    a0 = __builtin_amdgcn_mfma_f32_16x16x32_bf16(af0, K[0][0], a0, 0, 0, 0);
    a0 = __builtin_amdgcn_mfma_f32_16x16x32_bf16(af1, K[0][1], a0, 0, 0, 0);
    a1 = __builtin_amdgcn_mfma_f32_16x16x32_bf16(af0, K[1][0], a1, 0, 0, 0);
    a1 = __builtin_amdgcn_mfma_f32_16x16x32_bf16(af1, K[1][1], a1, 0, 0, 0);
    const int t0 = tb + c * 32;
#pragma unroll
    for (int nt = 0; nt < 2; ++nt)
#pragma unroll
      for (int i = 0; i < 4; ++i) {
        int t = t0 + nt * 16 + m15;
        float bv = (t == diagT[i]) ? dm[i] : b2f(cur[nt * 4 + i]);
        float a = (nt == 0) ? a0[i] : a1[i];
        float p = __expf(a + bv);
        lsum4[i] += p;
        pw[(s_l + i) * 36 + nt * 16 + m15] = f2b(p);
      }
    short8 pfr = *(const short8*)(&pw[m15 * 36 + q4 * 8]);
#pragma unroll
    for (int nd = 0; nd < 4; ++nd)
      oacc[nd] =
          __builtin_amdgcn_mfma_f32_16x16x32_bf16(pfr, V[nd], oacc[nd], 0, 0, 0);
  };

  // prologue: KV(0),KV(1) then Bh(0..3) — age order matches steady state
  short8 K0[2][2], V0[4], K1[2][2], V1[4], K2[2][2], V2[4], K3[2][2], V3[4];
  ushort B0[8], B1[8], B2[8], B3[8];
  ldKV(0, K0, V0);
  ldKV(1, K1, V1);
  __builtin_amdgcn_sched_barrier(0x38F);
  ldB(0, B0);
  ldB(1, B1);
  ldB(2, B2);
  ldB(3, B3);
  __builtin_amdgcn_sched_barrier(0x38F);
  for (int j = 0; j < 8; ++j) {
    const int c = j * 4;
    chunk(c, K0, V0, K2, V2, B0);
    chunk(c + 1, K1, V1, K3, V3, B1);
    chunk(c + 2, K2, V2, K0, V0, B2);
    chunk(c + 3, K3, V3, K1, V1, B3);
  }

  // row sums across the 16 t-lanes (m15 butterfly)
#pragma unroll
  for (int i = 0; i < 4; ++i) {
    float v = lsum4[i];
    v += __shfl_xor(v, 1, 64);
    v += __shfl_xor(v, 2, 64);
    v += __shfl_xor(v, 4, 64);
    v += __shfl_xor(v, 8, 64);
    lsum4[i] = v;
  }
  // combine T-halves
  if (th == 1) {
#pragma unroll
    for (int nd = 0; nd < 4; ++nd)
#pragma unroll
      for (int i = 0; i < 4; ++i)
        comb[st][s_l + i][nd * 16 + m15] = oacc[nd][i];
    if (m15 == 0)
#pragma unroll
      for (int i = 0; i < 4; ++i) csum[st * 16 + s_l + i] = lsum4[i];
  }
  __syncthreads();
  if (th == 0) {
#pragma unroll
    for (int i = 0; i < 4; ++i) lsum4[i] += csum[st * 16 + s_l + i];
#pragma unroll
    for (int nd = 0; nd < 4; ++nd)
#pragma unroll
      for (int i = 0; i < 4; ++i) {
        float v = oacc[nd][i] + comb[st][s_l + i][nd * 16 + m15];
        attn[((b << 10) + s0w + s_l + i) * 1024 + (h << 6) + nd * 16 + m15] =
            f2b(v / lsum4[i]);
      }
  }
}

// ---------------------------------------------------------------- launch ----
extern "C" void kernel_launch(void* const* d_in, const int* in_sizes, int n_in,
                              void* d_out, int out_size, void* d_ws,
                              size_t ws_size, hipStream_t stream) {
  const float* x = (const float*)d_in[0];
  const float* mem = (const float*)d_in[1];
  const float* mask = (const float*)d_in[2];
  const float* rel = (const float*)d_in[3];
  const float* Wq = (const float*)d_in[4];
  const float* bq = (const float*)d_in[5];
  const float* Wke = (const float*)d_in[6];
  const float* bke = (const float*)d_in[7];
  const float* Wkr = (const float*)d_in[8];
  const float* bkr = (const float*)d_in[9];
  const float* Wv = (const float*)d_in[10];
  const float* bv = (const float*)d_in[11];
  const float* Wo = (const float*)d_in[12];
  const float* bo = (const float*)d_in[13];
  float* out = (float*)d_out;

  ushort* ws = (ushort*)d_ws;
  ushort* xt = ws;                          // 4096x1024
  ushort* xbrel = xt + 4096 * 1024;         // [xb(2048); relb(2048)] x 1024
  ushort* WqT = xbrel + 4096 * 1024;
  ushort* WkeT = WqT + 1024 * 1024;
  ushort* WvT = WkeT + 1024 * 1024;         // must stay adjacent to WkeT
  ushort* WkrT = WvT + 1024 * 1024;
  ushort* WoT = WkrT + 1024 * 1024;
  ushort* kv = WoT + 1024 * 1024;           // [4096][2048]: K cols<1024, V^T region
  ushort* qr = kv + 4096 * 2048;            // [qbuf(2048); Qrb(2048)] x 1024
  ushort* attn = qr + 4096 * 1024;          // 2048x1024
  ushort* maskb = attn + 2048 * 1024;       // 1024x2048 bf16 pre-scaled
  ushort* Bh = maskb + 1024 * 2048;         // [b*16+h][1024 s][2048 u] bf16
  ushort* relb = xbrel + 2048 * 1024;
  ushort* Qrb = qr + 2048 * 1024;           // Qrel, pre-scaled by 1/8

  preproc_kernel<<<4096, 256, 0, stream>>>(x, mem, rel, mask, xt, xbrel, relb,
                                           maskb);
  transpose_cvt5_kernel<<<dim3(32, 32, 5), 256, 0, stream>>>(
      Wq, Wke, Wkr, Wv, Wo, WqT, WkeT, WkrT, WvT, WoT);

  gemm_fused_kernel<<<768, 256, 0, stream>>>(xt, xbrel, WkeT, WqT, WkrT, bke,
                                             bv, bq, bkr, kv, qr);

  bhat_kernel<<<dim3(16, 16, 16), 256, 0, stream>>>(qr, Qrb, maskb, Bh);

  attn_kernel<<<dim3(SEQ / 32, NH, BATCH), 256, 0, stream>>>(qr, kv, Bh, maskb,
                                                             attn);

  gemm64_kernel<1><<<dim3(32, 8), 256, 0, stream>>>(attn, WoT, bo, out, 2048,
                                                    1024, 1024);
}

// Round 9
// 314.125 us; speedup vs baseline: 1.1666x; 1.1666x over previous
//
#include <hip/hip_runtime.h>

typedef unsigned short ushort;
typedef unsigned int uint;
typedef __attribute__((ext_vector_type(8))) short short8;
typedef __attribute__((ext_vector_type(4))) float float4v;

#define D_MODEL 1024
#define NH 16
#define DH 64
#define BATCH 2
#define SEQ 1024
#define MEMLEN 1024
#define TOT 2048
#define BROW 2056              // Bh row stride: 2048 + 8 phase pad
#define PLN (1024 * BROW)      // Bh plane size (per b,h)

__device__ __forceinline__ float b2f(ushort u) {
  return __uint_as_float(((uint)u) << 16);
}
__device__ __forceinline__ ushort f2b(float f) {
  uint i = __float_as_uint(f);
  uint r = (i + 0x7fffu + ((i >> 16) & 1u)) >> 16;
  return (ushort)r;
}
__device__ __forceinline__ void gld16(const ushort* g, ushort* l) {
  __builtin_amdgcn_global_load_lds(
      (const __attribute__((address_space(1))) void*)g,
      (__attribute__((address_space(3))) void*)l, 16, 0, 0);
}

// ---------------- fused preprocessing: concat+cast, rel cast, mask cast -----
__global__ __launch_bounds__(256) void preproc_kernel(
    const float* __restrict__ x, const float* __restrict__ mem,
    const float* __restrict__ rel, const float* __restrict__ mask,
    ushort* __restrict__ xt, ushort* __restrict__ xb,
    ushort* __restrict__ relb, ushort* __restrict__ maskb) {
  const int bid = blockIdx.x;
  if (bid < 2048) {
    int idx = bid * 256 + threadIdx.x;
    int row = idx >> 7;
    int c8 = (idx & 127) << 3;
    int b = row >> 11;
    int i = row & 2047;
    const float* src = (i < MEMLEN) ? &mem[((b << 10) + i) * D_MODEL]
                                    : &x[((b << 10) + (i - MEMLEN)) * D_MODEL];
    float4 f0 = *(const float4*)(&src[c8]);
    float4 f1 = *(const float4*)(&src[c8 + 4]);
    ushort u[8] = {f2b(f0.x), f2b(f0.y), f2b(f0.z), f2b(f0.w),
                   f2b(f1.x), f2b(f1.y), f2b(f1.z), f2b(f1.w)};
    *(uint4*)(&xt[row * D_MODEL + c8]) = *(const uint4*)u;
    if (i >= MEMLEN)
      *(uint4*)(&xb[((b << 10) + (i - MEMLEN)) * D_MODEL + c8]) =
          *(const uint4*)u;
  } else if (bid < 3072) {
    int idx = (bid - 2048) * 256 + threadIdx.x;
    int base = idx << 3;
    float4 f0 = *(const float4*)(&rel[base]);
    float4 f1 = *(const float4*)(&rel[base + 4]);
    ushort u[8] = {f2b(f0.x), f2b(f0.y), f2b(f0.z), f2b(f0.w),
                   f2b(f1.x), f2b(f1.y), f2b(f1.z), f2b(f1.w)};
    *(uint4*)(&relb[base]) = *(const uint4*)u;
  } else {
    int idx = (bid - 3072) * 256 + threadIdx.x;
    int base = idx << 3;
    float4 f0 = *(const float4*)(&mask[base]);
    float4 f1 = *(const float4*)(&mask[base + 4]);
    ushort u[8] = {f2b(f0.x * -1e9f), f2b(f0.y * -1e9f), f2b(f0.z * -1e9f),
                   f2b(f0.w * -1e9f), f2b(f1.x * -1e9f), f2b(f1.y * -1e9f),
                   f2b(f1.z * -1e9f), f2b(f1.w * -1e9f)};
    *(uint4*)(&maskb[base]) = *(const uint4*)u;
  }
}

// --------------------------- 5x transpose + cast to bf16 (one launch) -------
__global__ __launch_bounds__(256) void transpose_cvt5_kernel(
    const float* __restrict__ W0, const float* __restrict__ W1,
    const float* __restrict__ W2, const float* __restrict__ W3,
    const float* __restrict__ W4, ushort* __restrict__ T0,
    ushort* __restrict__ T1, ushort* __restrict__ T2, ushort* __restrict__ T3,
    ushort* __restrict__ T4) {
  __shared__ ushort tle[32][33];
  const float* W;
  ushort* T;
  switch (blockIdx.z) {
    case 0: W = W0; T = T0; break;
    case 1: W = W1; T = T1; break;
    case 2: W = W2; T = T2; break;
    case 3: W = W3; T = T3; break;
    default: W = W4; T = T4; break;
  }
  const int bx = blockIdx.x * 32, by = blockIdx.y * 32;
  const int tx = threadIdx.x & 31, ty = threadIdx.x >> 5;
#pragma unroll
  for (int j = 0; j < 32; j += 8)
    tle[ty + j][tx] = f2b(W[(by + ty + j) * 1024 + bx + tx]);
  __syncthreads();
#pragma unroll
  for (int j = 0; j < 32; j += 8)
    T[(bx + ty + j) * 1024 + by + tx] = tle[tx][ty + j];
}

// --------------- fused projection GEMM: KV + q + qrel in one launch ---------
// seg0 (bid<512): K cols -> kv (scaled 0.125, bke); V cols -> written DIRECTLY
//   TRANSPOSED into kv's V-half via split-row mapping.
// seg1 (bid>=512): qr = xbrel @ (WqT | WkrT by row); qrel rows scaled 0.125.
__global__ __launch_bounds__(256) void gemm_fused_kernel(
    const ushort* __restrict__ xt, const ushort* __restrict__ xbrel,
    const ushort* __restrict__ WkeT, const ushort* __restrict__ WqT,
    const ushort* __restrict__ WkrT, const float* __restrict__ bke,
    const float* __restrict__ bv, const float* __restrict__ bq,
    const float* __restrict__ bkr, ushort* __restrict__ kv,
    ushort* __restrict__ qr) {
  __shared__ ushort As[128 * 32];
  __shared__ ushort Bs[128 * 32];
  const int bid = blockIdx.x;
  const bool seg0 = (bid < 512);
  const ushort* A;
  const ushort* BT;
  int m0, n0;
  if (seg0) {
    m0 = (bid & 31) * 128;
    n0 = (bid >> 5) * 128;
    A = xt;
    BT = WkeT;   // rows >=1024 fall through into adjacent WvT
  } else {
    int g = bid - 512;
    m0 = (g & 31) * 128;
    n0 = (g >> 5) * 128;
    A = xbrel;
    BT = (m0 < 2048) ? WqT : WkrT;
  }
  const int tid = threadIdx.x;
  const int w = tid >> 6, lane = tid & 63, m15 = lane & 15, q4 = lane >> 4;
  const int wm = w & 1, wn = w >> 1;
  float4v acc[4][4] = {};
  const int c0 = tid, c1 = tid + 256;
  const int r0 = c0 >> 2, u0 = (c0 & 3) * 8;
  const int r1 = c1 >> 2, u1 = (c1 & 3) * 8;

  for (int kk = 0; kk < 1024; kk += 32) {
    __syncthreads();
    gld16(&A[(m0 + r0) * 1024 + kk + u0], &As[c0 * 8]);
    gld16(&A[(m0 + r1) * 1024 + kk + u1], &As[c1 * 8]);
    gld16(&BT[(n0 + r0) * 1024 + kk + u0], &Bs[c0 * 8]);
    gld16(&BT[(n0 + r1) * 1024 + kk + u1], &Bs[c1 * 8]);
    __syncthreads();
    short8 af[4], bf[4];
#pragma unroll
    for (int i = 0; i < 4; ++i)
      af[i] = *(const short8*)(&As[(wm * 64 + i * 16 + m15) * 32 + q4 * 8]);
#pragma unroll
    for (int j = 0; j < 4; ++j)
      bf[j] = *(const short8*)(&Bs[(wn * 64 + j * 16 + m15) * 32 + q4 * 8]);
#pragma unroll
    for (int i = 0; i < 4; ++i)
#pragma unroll
      for (int j = 0; j < 4; ++j)
        acc[i][j] =
            __builtin_amdgcn_mfma_f32_16x16x32_bf16(af[i], bf[j], acc[i][j], 0, 0, 0);
  }
#pragma unroll
  for (int j = 0; j < 4; ++j) {
    int col = n0 + wn * 64 + j * 16 + m15;
    if (seg0) {
      if (col < 1024) {
        float bb = bke[col];
#pragma unroll
        for (int i = 0; i < 4; ++i) {
          int rowb = m0 + wm * 64 + i * 16 + q4 * 4;
#pragma unroll
          for (int r = 0; r < 4; ++r)
            kv[(rowb + r) * 2048 + col] = f2b((acc[i][j][r] + bb) * 0.125f);
        }
      } else {
        float bb = bv[col - 1024];
#pragma unroll
        for (int i = 0; i < 4; ++i) {
          int rowb = m0 + wm * 64 + i * 16 + q4 * 4;
          int dg = ((rowb >> 11) << 10) + (col - 1024);
          size_t prow = (size_t)(dg * 2 + ((rowb >> 10) & 1)) * 2048 + 1024 +
                        (rowb & 1023);
          uint lo = (uint)f2b(acc[i][j][0] + bb) |
                    ((uint)f2b(acc[i][j][1] + bb) << 16);
          uint hi = (uint)f2b(acc[i][j][2] + bb) |
                    ((uint)f2b(acc[i][j][3] + bb) << 16);
          *(uint2*)(&kv[prow]) = make_uint2(lo, hi);
        }
      }
    } else {
      float bb = (m0 < 2048) ? bq[col] : bkr[col];
      float sc = (m0 < 2048) ? 1.0f : 0.125f;
#pragma unroll
      for (int i = 0; i < 4; ++i) {
        int rowb = m0 + wm * 64 + i * 16 + q4 * 4;
#pragma unroll
        for (int r = 0; r < 4; ++r)
          qr[(rowb + r) * 1024 + col] = f2b((acc[i][j][r] + bb) * sc);
      }
    }
  }
}

// -------------------------------------- 64x128-tile GEMM (output proj) ------
template <int EPI>
__global__ __launch_bounds__(256) void gemm64_kernel(
    const ushort* __restrict__ A, const ushort* __restrict__ BT,
    const float* __restrict__ bias, void* __restrict__ Cout, int M, int N,
    int K) {
  __shared__ ushort As[64 * 32];
  __shared__ ushort Bs[128 * 32];
  const int m0 = blockIdx.x * 64, n0 = blockIdx.y * 128;
  const int tid = threadIdx.x;
  const int w = tid >> 6, lane = tid & 63, m15 = lane & 15, q4 = lane >> 4;
  float4v acc[4][2] = {};
  const int ra = tid >> 2, ua = (tid & 3) * 8;
  const int c0 = tid, c1 = tid + 256;
  const int rb0 = c0 >> 2, ub0 = (c0 & 3) * 8;
  const int rb1 = c1 >> 2, ub1 = (c1 & 3) * 8;

  for (int kk = 0; kk < K; kk += 32) {
    __syncthreads();
    gld16(&A[(m0 + ra) * K + kk + ua], &As[tid * 8]);
    gld16(&BT[(n0 + rb0) * K + kk + ub0], &Bs[c0 * 8]);
    gld16(&BT[(n0 + rb1) * K + kk + ub1], &Bs[c1 * 8]);
    __syncthreads();
    short8 bf[2];
#pragma unroll
    for (int j = 0; j < 2; ++j)
      bf[j] = *(const short8*)(&Bs[(w * 32 + j * 16 + m15) * 32 + q4 * 8]);
#pragma unroll
    for (int i = 0; i < 4; ++i) {
      short8 af = *(const short8*)(&As[(i * 16 + m15) * 32 + q4 * 8]);
#pragma unroll
      for (int j = 0; j < 2; ++j)
        acc[i][j] =
            __builtin_amdgcn_mfma_f32_16x16x32_bf16(af, bf[j], acc[i][j], 0, 0, 0);
    }
  }
#pragma unroll
  for (int j = 0; j < 2; ++j) {
    int col = n0 + w * 32 + j * 16 + m15;
    float bv = bias[col];
#pragma unroll
    for (int i = 0; i < 4; ++i) {
      int rowb = m0 + i * 16 + q4 * 4;
#pragma unroll
      for (int r = 0; r < 4; ++r) {
        float v = acc[i][j][r] + bv;
        if (EPI == 1)
          ((float*)Cout)[(rowb + r) * N + col] = v;
        else
          ((ushort*)Cout)[(rowb + r) * N + col] = f2b(v);
      }
    }
  }
}

// -------------- Bhat batched GEMM + mask fold, phase-padded rows ------------
// Bh[plane][sp][u] = q[sp].Qrel[u] + mask of the consumer cell (band-A and
// wrap consumers are disjoint). Row sp stored at byte phase (sp+1)&7, stride
// BROW, so every 8-elem t-segment of band A (u=t-sp+1023) AND band B
// (row sp+1, u=t-sp-1026) is 16B-aligned for the consumer's gld16 staging.
__global__ __launch_bounds__(256) void bhat_kernel(
    const ushort* __restrict__ q, const ushort* __restrict__ Qrb,
    const ushort* __restrict__ maskb, ushort* __restrict__ Bh) {
  __shared__ ushort As[2 * 128 * 32];
  __shared__ ushort Bs[2 * 128 * 32];
  const int bs0 = blockIdx.x * 128, u0 = blockIdx.y * 128, h = blockIdx.z;
  const int tid = threadIdx.x;
  const int w = tid >> 6, lane = tid & 63, m15 = lane & 15, q4 = lane >> 4;
  const int wm = w & 1, wn = w >> 1;

#pragma unroll
  for (int c = 0; c < 4; ++c) {
    int unit = c * 256 + tid;               // flat LDS ushort = unit*8
    int row = (unit >> 2) & 127, kh = unit >> 9, cu = unit & 3;
    gld16(&q[(bs0 + row) * 1024 + (h << 6) + kh * 32 + cu * 8], &As[unit * 8]);
    gld16(&Qrb[(u0 + row) * 1024 + (h << 6) + kh * 32 + cu * 8], &Bs[unit * 8]);
  }
  __syncthreads();

  float4v acc[4][4] = {};
#pragma unroll
  for (int kh = 0; kh < 2; ++kh) {
    short8 af[4], bf[4];
#pragma unroll
    for (int i = 0; i < 4; ++i)
      af[i] = *(const short8*)(&As[kh * 4096 + (wm * 64 + i * 16 + m15) * 32 + q4 * 8]);
#pragma unroll
    for (int j = 0; j < 4; ++j)
      bf[j] = *(const short8*)(&Bs[kh * 4096 + (wn * 64 + j * 16 + m15) * 32 + q4 * 8]);
#pragma unroll
    for (int i = 0; i < 4; ++i)
#pragma unroll
      for (int j = 0; j < 4; ++j)
        acc[i][j] =
            __builtin_amdgcn_mfma_f32_16x16x32_bf16(af[i], bf[j], acc[i][j], 0, 0, 0);
  }
  const int b = bs0 >> 10;
  const int s0loc = bs0 & 1023;
  const int pbase = ((b << 4) + h) * PLN;
#pragma unroll
  for (int j = 0; j < 4; ++j) {
    int u = u0 + wn * 64 + j * 16 + m15;
#pragma unroll
    for (int i = 0; i < 4; ++i) {
      int spb = s0loc + wm * 64 + i * 16 + q4 * 4;
#pragma unroll
      for (int r = 0; r < 4; ++r) {
        int sp = spb + r;
        bool selA = (u >= 1023 - sp);
        int mrow = selA ? sp : (sp > 0 ? sp - 1 : 0);
        int mcol = selA ? (u + sp - 1023) : (u + sp + 1025);
        float mval = b2f(maskb[mrow * 2048 + mcol]);
        Bh[pbase + sp * BROW + ((sp + 1) & 7) + u] = f2b(acc[i][j][r] + mval);
      }
    }
  }
}

// ------ fused attention v9: block-cooperative gld_lds + counted vmcnt -------
// Block = 64 s-rows (4 waves x 16) sweeping all T in 64 chunks of 32.
// All K/V/Bh traffic is async global_load_lds into a 4-slot LDS ring, staged
// 3 chunks ahead. Steady state: exactly 4 unconditional gld16/thread/chunk,
// then s_waitcnt vmcnt(12) (NEVER 0) + raw s_barrier -> data ready; compute;
// barrier -> slot reusable. Zero register VMEM in the loop. Bh gather uses
// per-lane diagonal SOURCE addresses (dest linear), 16B-aligned via BROW
// phase padding; LDS reads XOR-swizzled to ~2-way. Straddle chunks
// (block-uniform, ~3/64) select per-element between band buffers + diag mask.
__global__ __launch_bounds__(256) void attn_kernel(
    const ushort* __restrict__ qb, const ushort* __restrict__ kv,
    const ushort* __restrict__ Bh, const ushort* __restrict__ maskb,
    ushort* __restrict__ attn) {
  __shared__ ushort Ks[4][32 * 64];
  __shared__ ushort Vs[4][64 * 32];
  __shared__ ushort BA[4][64 * 32];
  __shared__ ushort BB[4][64 * 32];
  __shared__ ushort Pp[4][16 * 36];

  const int tid = threadIdx.x;
  const int w = tid >> 6, lane = tid & 63, m15 = lane & 15, q4 = lane >> 4;
  const int s0 = blockIdx.x * 64;
  const int h = blockIdx.y, b = blockIdx.z;
  const int s_l = q4 * 4;
  const int sw0 = s0 + w * 16;

  const ushort* qp = &qb[((b << 10) + sw0 + m15) * 1024 + (h << 6) + q4 * 8];
  const short8 af0 = *(const short8*)qp;
  const short8 af1 = *(const short8*)(qp + 32);

  const ushort* kvb = &kv[((size_t)(b << 11) * 2048) + (h << 6)];
  const size_t vbase = ((size_t)((b << 10) + (h << 6)) * 2) * 2048;
  const int pbase = ((b << 4) + h) * PLN;
  ushort* pw = &Pp[w][0];

  // diag mask values for this wave's rows
  float dm[4];
  int diagT[4];
#pragma unroll
  for (int i = 0; i < 4; ++i) {
    int s = sw0 + s_l + i;
    diagT[i] = s + 1025;
    dm[i] = (diagT[i] <= 2047) ? b2f(maskb[s * 2048 + diagT[i]]) : 0.f;
  }
  // drain register loads (q, dm) BEFORE any staging so no later compiler
  // wait can force-drain the staged gld16 queue
  asm volatile("s_waitcnt vmcnt(0)" ::: "memory");
  __builtin_amdgcn_sched_barrier(0);

  // stage lane geometry (per-lane source, linear dest)
  const int rK = tid >> 3, cK = tid & 7;   // K: 32 t-rows x 8 d-segs
  const int rV = tid >> 2, cV = tid & 3;   // V: 64 d-rows x 4 t-segs
  const int rB = tid >> 2, cB = tid & 3;   // B: 64 s-rows x 4 t-segs
  const int sB = s0 + rB;
  const int offA_l = pbase + sB * BROW + ((sB + 1) & 7) - sB + 1023;
  const int offB_l = pbase + (sB + 1) * BROW + ((sB + 2) & 7) - sB - 1026;
  const int segK = cK ^ (rK & 7);
  const int segV = cV ^ ((rV >> 2) & 3);
  const int segB = cB ^ ((rB >> 2) & 3);

  float lsum4[4] = {0.f, 0.f, 0.f, 0.f};
  float4v oacc[4] = {};

#define STAGE(c, sl)                                                          \
  {                                                                           \
    const int t0_ = (c) * 32;                                                 \
    gld16(&kvb[(size_t)(t0_ + rK) * 2048 + segK * 8], &Ks[sl][tid * 8]);      \
    gld16(&kv[vbase + ((size_t)rV * 2 + (t0_ >> 10)) * 2048 + 1024 +          \
              (t0_ & 1023) + segV * 8],                                       \
          &Vs[sl][tid * 8]);                                                  \
    int t8_ = t0_ + segB * 8;                                                 \
    int offa_ = (t8_ <= sB + 1025) ? offA_l : offB_l;                         \
    gld16(&Bh[offa_ + t8_], &BA[sl][tid * 8]);                                \
    bool str_ = (t0_ + 31 >= s0 + 1018) && (t0_ <= s0 + 1088);                \
    int offb_ = str_ ? offB_l : offa_;                                        \
    gld16(&Bh[offb_ + t8_], &BB[sl][tid * 8]);                                \
  }

#define WAITV(n)                                                              \
  __builtin_amdgcn_sched_barrier(0);                                          \
  asm volatile("s_waitcnt vmcnt(" #n ")" ::: "memory");                       \
  __builtin_amdgcn_sched_barrier(0);                                          \
  __builtin_amdgcn_s_barrier();

  auto compute = [&](int c, int sl) {
    const int t0 = c * 32;
    short8 Kf[2][2];
#pragma unroll
    for (int nt = 0; nt < 2; ++nt)
#pragma unroll
      for (int ko = 0; ko < 2; ++ko)
        Kf[nt][ko] = *(const short8*)(&Ks[sl][(nt * 16 + m15) * 64 +
                                              (((q4 + 4 * ko) ^ (m15 & 7)) << 3)]);
    short8 Vf[4];
#pragma unroll
    for (int nd = 0; nd < 4; ++nd) {
      int d = nd * 16 + m15;
      Vf[nd] = *(const short8*)(&Vs[sl][d * 32 + ((q4 ^ ((d >> 2) & 3)) << 3)]);
    }
    float4v a0 = {}, a1 = {};
    a0 = __builtin_amdgcn_mfma_f32_16x16x32_bf16(af0, Kf[0][0], a0, 0, 0, 0);
    a0 = __builtin_amdgcn_mfma_f32_16x16x32_bf16(af1, Kf[0][1], a0, 0, 0, 0);
    a1 = __builtin_amdgcn_mfma_f32_16x16x32_bf16(af0, Kf[1][0], a1, 0, 0, 0);
    a1 = __builtin_amdgcn_mfma_f32_16x16x32_bf16(af1, Kf[1][1], a1, 0, 0, 0);
    const bool strad = (t0 + 31 >= s0 + 1018) && (t0 <= s0 + 1088);
    if (!strad) {
#pragma unroll
      for (int nt = 0; nt < 2; ++nt)
#pragma unroll
        for (int i = 0; i < 4; ++i) {
          int rr = (w << 4) + s_l + i;
          int cc = nt * 16 + m15;
          ushort bu = BA[sl][rr * 32 + (((cc >> 3) ^ q4) << 3) + (cc & 7)];
          float a = nt ? a1[i] : a0[i];
          float p = __expf(a + b2f(bu));
          lsum4[i] += p;
          pw[(s_l + i) * 36 + cc] = f2b(p);
        }
    } else {
#pragma unroll
      for (int nt = 0; nt < 2; ++nt)
#pragma unroll
        for (int i = 0; i < 4; ++i) {
          int rr = (w << 4) + s_l + i;
          int cc = nt * 16 + m15;
          int t = t0 + cc;
          int li = rr * 32 + (((cc >> 3) ^ q4) << 3) + (cc & 7);
          int s = sw0 + s_l + i;
          float va = b2f(BA[sl][li]);
          float vb = b2f(BB[sl][li]);
          int t8 = t & ~7;
          float bval = (t == diagT[i])
                           ? dm[i]
                           : ((t > diagT[i] && t8 <= s + 1025) ? vb : va);
          float a = nt ? a1[i] : a0[i];
          float p = __expf(a + bval);
          lsum4[i] += p;
          pw[(s_l + i) * 36 + cc] = f2b(p);
        }
    }
    short8 pfr = *(const short8*)(&pw[m15 * 36 + q4 * 8]);
#pragma unroll
    for (int nd = 0; nd < 4; ++nd)
      oacc[nd] =
          __builtin_amdgcn_mfma_f32_16x16x32_bf16(pfr, Vf[nd], oacc[nd], 0, 0, 0);
  };

  // prologue: 3 stages in flight
  STAGE(0, 0);
  STAGE(1, 1);
  STAGE(2, 2);
  // steady state: chunks 0..59, stage c+3, wait own oldest stage (12 left)
  for (int j = 0; j < 15; ++j) {
    const int c = j * 4;
    STAGE(c + 3, 3); WAITV(12); compute(c, 0); __builtin_amdgcn_s_barrier();
    STAGE(c + 4, 0); WAITV(12); compute(c + 1, 1); __builtin_amdgcn_s_barrier();
    STAGE(c + 5, 1); WAITV(12); compute(c + 2, 2); __builtin_amdgcn_s_barrier();
    STAGE(c + 6, 2); WAITV(12); compute(c + 3, 3); __builtin_amdgcn_s_barrier();
  }
  // epilogue: chunks 60..63
  STAGE(63, 3); WAITV(12); compute(60, 0); __builtin_amdgcn_s_barrier();
  WAITV(8);  compute(61, 1); __builtin_amdgcn_s_barrier();
  WAITV(4);  compute(62, 2); __builtin_amdgcn_s_barrier();
  WAITV(0);  compute(63, 3);

  // row sums across the 16 t-lanes (m15 butterfly)
#pragma unroll
  for (int i = 0; i < 4; ++i) {
    float v = lsum4[i];
    v += __shfl_xor(v, 1, 64);
    v += __shfl_xor(v, 2, 64);
    v += __shfl_xor(v, 4, 64);
    v += __shfl_xor(v, 8, 64);
    lsum4[i] = v;
  }
  // each wave owns its 16 rows completely: direct write
#pragma unroll
  for (int nd = 0; nd < 4; ++nd)
#pragma unroll
    for (int i = 0; i < 4; ++i)
      attn[((b << 10) + sw0 + s_l + i) * 1024 + (h << 6) + nd * 16 + m15] =
          f2b(oacc[nd][i] / lsum4[i]);
#undef STAGE
#undef WAITV
}

// ---------------------------------------------------------------- launch ----
extern "C" void kernel_launch(void* const* d_in, const int* in_sizes, int n_in,
                              void* d_out, int out_size, void* d_ws,
                              size_t ws_size, hipStream_t stream) {
  const float* x = (const float*)d_in[0];
  const float* mem = (const float*)d_in[1];
  const float* mask = (const float*)d_in[2];
  const float* rel = (const float*)d_in[3];
  const float* Wq = (const float*)d_in[4];
  const float* bq = (const float*)d_in[5];
  const float* Wke = (const float*)d_in[6];
  const float* bke = (const float*)d_in[7];
  const float* Wkr = (const float*)d_in[8];
  const float* bkr = (const float*)d_in[9];
  const float* Wv = (const float*)d_in[10];
  const float* bv = (const float*)d_in[11];
  const float* Wo = (const float*)d_in[12];
  const float* bo = (const float*)d_in[13];
  float* out = (float*)d_out;

  ushort* ws = (ushort*)d_ws;
  ushort* xt = ws;                          // 4096x1024
  ushort* xbrel = xt + 4096 * 1024;         // [xb(2048); relb(2048)] x 1024
  ushort* WqT = xbrel + 4096 * 1024;
  ushort* WkeT = WqT + 1024 * 1024;
  ushort* WvT = WkeT + 1024 * 1024;         // must stay adjacent to WkeT
  ushort* WkrT = WvT + 1024 * 1024;
  ushort* WoT = WkrT + 1024 * 1024;
  ushort* kv = WoT + 1024 * 1024;           // [4096][2048]: K cols<1024, V^T region
  ushort* qr = kv + 4096 * 2048;            // [qbuf(2048); Qrb(2048)] x 1024
  ushort* attn = qr + 4096 * 1024;          // 2048x1024
  ushort* maskb = attn + 2048 * 1024;       // 1024x2048 bf16 pre-scaled
  ushort* Bh = maskb + 1024 * 2048;         // 32 planes x 1024 x BROW (+pad row)
  ushort* relb = xbrel + 2048 * 1024;
  ushort* Qrb = qr + 2048 * 1024;           // Qrel, pre-scaled by 1/8

  preproc_kernel<<<4096, 256, 0, stream>>>(x, mem, rel, mask, xt, xbrel, relb,
                                           maskb);
  transpose_cvt5_kernel<<<dim3(32, 32, 5), 256, 0, stream>>>(
      Wq, Wke, Wkr, Wv, Wo, WqT, WkeT, WkrT, WvT, WoT);

  gemm_fused_kernel<<<768, 256, 0, stream>>>(xt, xbrel, WkeT, WqT, WkrT, bke,
                                             bv, bq, bkr, kv, qr);

  bhat_kernel<<<dim3(16, 16, 16), 256, 0, stream>>>(qr, Qrb, maskb, Bh);

  attn_kernel<<<dim3(16, NH, BATCH), 256, 0, stream>>>(qr, kv, Bh, maskb,
                                                       attn);

  gemm64_kernel<1><<<dim3(32, 8), 256, 0, stream>>>(attn, WoT, bo, out, 2048,
                                                    1024, 1024);
}